// Round 6
// baseline (2788.063 us; speedup 1.0000x reference)
//
#include <hip/hip_runtime.h>

#define Bn 4
#define Nn 4096000
#define Kn 409664
#define R0c 3686399u   // rank of v_lo; mask == key > key_lo exactly (adjacent order stats)
#define NWC 4000       // 1024-element chunks per sample
#define CAPS 262144    // candidate cap per sample (expect ~128K for uniform input)

// ws offsets (u32 units)
#define H1_OFF 0                      // Bn*8192  (13-bit digit)
#define H2_OFF (H1_OFF + Bn*8192)     // Bn*2048  (mid 11 bits of candidates)
#define H3_OFF (H2_OFF + Bn*2048)     // Bn*256   (low 8 bits)
#define ST_OFF (H3_OFF + Bn*256)      // Bn*2 {prefix/key, rem/lo19}
#define CNT_OFF (ST_OFF + Bn*2)       // Bn  per-sample totals
#define CN_OFF (CNT_OFF + Bn)         // Bn  candidate counters
#define BC_OFF (CN_OFF + Bn)          // Bn*NWC chunk counts -> exclusive prefix
#define CAND_OFF (BC_OFF + Bn*NWC)    // Bn*CAPS packed (wc<<19)|low19
#define ZERO_END BC_OFF               // memset covers H1..CN

#define OUT_SP  ((size_t)Bn * Kn * 5)
#define OUT_VAL ((size_t)Bn * Kn * 9)

__device__ __forceinline__ unsigned fkey(float x) {
    unsigned u = __float_as_uint(x);
    return u ^ ((unsigned)((int)u >> 31) | 0x80000000u);
}

// ---------------- hist1: top 13 bits, 1 shared LDS copy, grid-strided ----------------
__global__ __launch_bounds__(256) void hist1_k(const float* __restrict__ cube,
                                               unsigned* __restrict__ ws) {
    __shared__ unsigned h[8192];
    int tid = threadIdx.x, blk = blockIdx.x;
    int b = blk / 250, c = blk % 250;
    for (int j = tid; j < 8192; j += 256) h[j] = 0;
    __syncthreads();
    const float4* p = (const float4*)(cube + (size_t)b * Nn + (size_t)c * 16384);
    for (int it = 0; it < 16; ++it) {
        float4 v = p[it * 256 + tid];
        atomicAdd(&h[fkey(v.x) >> 19], 1u);
        atomicAdd(&h[fkey(v.y) >> 19], 1u);
        atomicAdd(&h[fkey(v.z) >> 19], 1u);
        atomicAdd(&h[fkey(v.w) >> 19], 1u);
    }
    __syncthreads();
    unsigned* g = ws + H1_OFF + b * 8192;
    for (int j = tid; j < 8192; j += 256) if (h[j]) atomicAdd(&g[j], h[j]);
}

// ---------------- pick1: walk 8192 bins -> p13, rem ----------------
__global__ __launch_bounds__(256) void pick1_k(unsigned* __restrict__ ws) {
    __shared__ unsigned sh[256];
    int tid = threadIdx.x, b = blockIdx.x;
    const unsigned* hist = ws + H1_OFF + b * 8192;
    unsigned loc[32], lsum = 0;
    for (int j = 0; j < 32; ++j) { loc[j] = hist[tid * 32 + j]; lsum += loc[j]; }
    sh[tid] = lsum; __syncthreads();
    for (int off = 1; off < 256; off <<= 1) {
        unsigned v = (tid >= off) ? sh[tid - off] : 0u; __syncthreads();
        sh[tid] += v; __syncthreads();
    }
    unsigned base = tid ? sh[tid - 1] : 0u;
    if (R0c >= base && R0c < base + lsum) {
        unsigned cacc = base;
        for (int j = 0; j < 32; ++j) {
            if (R0c < cacc + loc[j]) {
                ws[ST_OFF + b * 2] = (unsigned)(tid * 32 + j);
                ws[ST_OFF + b * 2 + 1] = R0c - cacc;
                break;
            }
            cacc += loc[j];
        }
    }
}

// ---------------- pass2: per-chunk A-counts + wave-aggregated candidate compaction ----------------
__global__ __launch_bounds__(256) void pass2_k(const float* __restrict__ cube,
                                               unsigned* __restrict__ ws) {
    int tid = threadIdx.x, blk = blockIdx.x;
    int lane = tid & 63, wid = tid >> 6;
    int b = blk / 1000, c = blk % 1000;
    unsigned p13 = ws[ST_OFF + b * 2];
    int wc = c * 4 + wid;
    const float4* p = (const float4*)(cube + (size_t)b * Nn + (size_t)wc * 1024);
    float4 v0 = p[lane], v1 = p[64 + lane], v2 = p[128 + lane], v3 = p[192 + lane];
    float vv[16] = {v0.x, v0.y, v0.z, v0.w, v1.x, v1.y, v1.z, v1.w,
                    v2.x, v2.y, v2.z, v2.w, v3.x, v3.y, v3.z, v3.w};
    unsigned acnt = 0;
    unsigned* cand = ws + CAND_OFF + (size_t)b * CAPS;
#pragma unroll
    for (int q = 0; q < 16; ++q) {
        unsigned k = fkey(vv[q]);
        unsigned top = k >> 19;
        acnt += (top > p13) ? 1u : 0u;
        bool is_c = (top == p13);
        unsigned long long bal = __ballot(is_c);
        unsigned n = (unsigned)__popcll(bal);
        if (n) {
            unsigned base;
            if (lane == 0) base = atomicAdd(&ws[CN_OFF + b], n);
            base = __shfl(base, 0, 64);
            if (is_c) {
                unsigned slot = base + (unsigned)__popcll(bal & ((1ull << lane) - 1ull));
                if (slot < CAPS)
                    cand[slot] = ((unsigned)wc << 19) | (k & 0x7FFFFu);
            }
        }
    }
    for (int off = 32; off > 0; off >>= 1) acnt += __shfl_down(acnt, off, 64);
    if (lane == 0) ws[BC_OFF + b * NWC + wc] = acnt;
}

// ---------------- candh2: mid-11 hist over candidates ----------------
__global__ __launch_bounds__(256) void candh2_k(unsigned* __restrict__ ws) {
    __shared__ unsigned h[2048];
    int tid = threadIdx.x, blk = blockIdx.x;
    int b = blk / 32, c = blk % 32;
    unsigned n = ws[CN_OFF + b]; if (n > CAPS) n = CAPS;
    for (int j = tid; j < 2048; j += 256) h[j] = 0;
    __syncthreads();
    const unsigned* cand = ws + CAND_OFF + (size_t)b * CAPS;
    for (unsigned t = c * 256 + tid; t < n; t += 32 * 256)
        atomicAdd(&h[(cand[t] >> 8) & 0x7FFu], 1u);
    __syncthreads();
    unsigned* g = ws + H2_OFF + b * 2048;
    for (int j = tid; j < 2048; j += 256) if (h[j]) atomicAdd(&g[j], h[j]);
}

__global__ __launch_bounds__(256) void pick2_k(unsigned* __restrict__ ws) {
    __shared__ unsigned sh[256];
    int tid = threadIdx.x, b = blockIdx.x;
    const unsigned* hist = ws + H2_OFF + b * 2048;
    unsigned r = ws[ST_OFF + b * 2 + 1];
    unsigned pref = ws[ST_OFF + b * 2];
    unsigned loc[8], lsum = 0;
    for (int j = 0; j < 8; ++j) { loc[j] = hist[tid * 8 + j]; lsum += loc[j]; }
    sh[tid] = lsum; __syncthreads();
    for (int off = 1; off < 256; off <<= 1) {
        unsigned v = (tid >= off) ? sh[tid - off] : 0u; __syncthreads();
        sh[tid] += v; __syncthreads();
    }
    unsigned base = tid ? sh[tid - 1] : 0u;
    if (r >= base && r < base + lsum) {
        unsigned cacc = base;
        for (int j = 0; j < 8; ++j) {
            if (r < cacc + loc[j]) {
                ws[ST_OFF + b * 2] = (pref << 11) | (unsigned)(tid * 8 + j);
                ws[ST_OFF + b * 2 + 1] = r - cacc;
                break;
            }
            cacc += loc[j];
        }
    }
}

// ---------------- candh3: low-8 hist of candidates matching sel11 (few hundred) ----------------
__global__ __launch_bounds__(256) void candh3_k(unsigned* __restrict__ ws) {
    int tid = threadIdx.x, blk = blockIdx.x;
    int b = blk / 8, c = blk % 8;
    unsigned sel11 = ws[ST_OFF + b * 2] & 0x7FFu;
    unsigned n = ws[CN_OFF + b]; if (n > CAPS) n = CAPS;
    const unsigned* cand = ws + CAND_OFF + (size_t)b * CAPS;
    for (unsigned t = c * 256 + tid; t < n; t += 8 * 256) {
        unsigned e = cand[t];
        if (((e >> 8) & 0x7FFu) == sel11)
            atomicAdd(&ws[H3_OFF + b * 256 + (e & 0xFFu)], 1u);
    }
}

// ---------------- pick3: 256 bins -> final key_lo ----------------
__global__ __launch_bounds__(256) void pick3_k(unsigned* __restrict__ ws) {
    __shared__ unsigned sh[256];
    int tid = threadIdx.x, b = blockIdx.x;
    unsigned loc = ws[H3_OFF + b * 256 + tid];
    unsigned r = ws[ST_OFF + b * 2 + 1];
    unsigned pref = ws[ST_OFF + b * 2];   // (p13<<11)|sel11
    sh[tid] = loc; __syncthreads();
    for (int off = 1; off < 256; off <<= 1) {
        unsigned v = (tid >= off) ? sh[tid - off] : 0u; __syncthreads();
        sh[tid] += v; __syncthreads();
    }
    unsigned base = tid ? sh[tid - 1] : 0u;
    if (r >= base && r < base + loc) {
        unsigned key = (pref << 8) | (unsigned)tid;
        ws[ST_OFF + b * 2] = key;               // full 32-bit key_lo
        ws[ST_OFF + b * 2 + 1] = key & 0x7FFFFu; // lo19 for fixup
    }
}

// ---------------- fixup: add selected candidates to their chunk counts ----------------
__global__ __launch_bounds__(256) void fixup_k(unsigned* __restrict__ ws) {
    int tid = threadIdx.x, blk = blockIdx.x;
    int b = blk / 16, c = blk % 16;
    unsigned lo19 = ws[ST_OFF + b * 2 + 1];
    unsigned n = ws[CN_OFF + b]; if (n > CAPS) n = CAPS;
    const unsigned* cand = ws + CAND_OFF + (size_t)b * CAPS;
    for (unsigned t = c * 256 + tid; t < n; t += 16 * 256) {
        unsigned e = cand[t];
        if ((e & 0x7FFFFu) > lo19)
            atomicAdd(&ws[BC_OFF + b * NWC + (e >> 19)], 1u);
    }
}

// ---------------- scan: exclusive prefix of 4000 chunk counts per sample ----------------
__global__ __launch_bounds__(256) void scan_k(unsigned* __restrict__ ws) {
    __shared__ unsigned sh[256];
    int tid = threadIdx.x, b = blockIdx.x;
    unsigned* bc = ws + BC_OFF + b * NWC;
    unsigned loc[16], lsum = 0;
    for (int j = 0; j < 16; ++j) {
        int idx = tid * 16 + j;
        loc[j] = (idx < NWC) ? bc[idx] : 0u;
        lsum += loc[j];
    }
    sh[tid] = lsum; __syncthreads();
    for (int off = 1; off < 256; off <<= 1) {
        unsigned v = (tid >= off) ? sh[tid - off] : 0u; __syncthreads();
        sh[tid] += v; __syncthreads();
    }
    unsigned run = tid ? sh[tid - 1] : 0u;
    for (int j = 0; j < 16; ++j) {
        int idx = tid * 16 + j;
        if (idx < NWC) bc[idx] = run;
        run += loc[j];
    }
    if (tid == 255) ws[CNT_OFF + b] = sh[255];
}

// ---------------- scatter: ordered compaction, mult-only math, incremental coords ----------------
__global__ __launch_bounds__(256) void scatter_k(const float* __restrict__ cube,
                                                 const float* __restrict__ dop,
                                                 float* __restrict__ out,
                                                 const unsigned* __restrict__ ws) {
    int tid = threadIdx.x, blk = blockIdx.x;
    int lane = tid & 63, wid = tid >> 6;
    int b = blk / 1000, c = blk % 1000;
    const float* cb = cube + (size_t)b * Nn;
    const float* db = dop + (size_t)b * Nn;
    unsigned keylo = ws[ST_OFF + b * 2];
    int wc = c * 4 + wid;
    unsigned run = ws[BC_OFF + b * NWC + wc];
    int base = wc * 1024;

    // decouple loads from the serial ballot/rank chain
    float xv[16];
#pragma unroll
    for (int it = 0; it < 16; ++it) xv[it] = cb[base + it * 64 + lane];

    // incremental coordinates: one div/mod set, then +64 carry per iteration
    int i = base + lane;
    int xi = i % 320;
    int t2 = i / 320;
    int yi = t2 % 320;
    int zi = t2 / 320;

#pragma unroll
    for (int it = 0; it < 16; ++it) {
        float x = xv[it];
        bool m = fkey(x) > keylo;
        unsigned long long bal = __ballot(m);
        if (m) {
            unsigned k = run + (unsigned)__popcll(bal & ((1ull << lane) - 1ull));
            size_t row = (size_t)b * Kn + k;
            float* f = out + row * 5;
            f[0] = (float)xi * (72.0f / 320.0f);
            f[1] = (float)yi * (32.0f / 320.0f);
            f[2] = (float)zi * (8.0f / 40.0f);
            f[3] = x * 1e-13f;
            f[4] = db[i] - 1.9326f;
            float4* s4 = (float4*)(out + OUT_SP + row * 4);
            *s4 = make_float4((float)b, (float)zi, (float)yi, (float)xi);
            out[OUT_VAL + row] = 1.0f;
        }
        run += (unsigned)__popcll(bal);
        i += 64;
        xi += 64;
        if (xi >= 320) {
            xi -= 320;
            if (++yi == 320) { yi = 0; ++zi; }
        }
    }
    // tail fill (outputs re-poisoned before every launch)
    for (int g = blk * 256 + tid; g < Bn * Kn; g += 4000 * 256) {
        int bb = g / Kn;
        int k = g - bb * Kn;
        if ((unsigned)k >= ws[CNT_OFF + bb]) {
            size_t row = (size_t)g;
            float* f = out + row * 5;
            f[0] = 0.f; f[1] = 0.f; f[2] = 0.f; f[3] = 0.f; f[4] = 0.f;
            float4* s4 = (float4*)(out + OUT_SP + row * 4);
            *s4 = make_float4(0.f, 0.f, 0.f, 0.f);
            out[OUT_VAL + row] = 0.f;
        }
    }
}

extern "C" void kernel_launch(void* const* d_in, const int* in_sizes, int n_in,
                              void* d_out, int out_size, void* d_ws, size_t ws_size,
                              hipStream_t stream) {
    const float* cube = (const float*)d_in[0];
    const float* dop = (const float*)d_in[1];
    float* out = (float*)d_out;
    unsigned* ws = (unsigned*)d_ws;

    // zero H1/H2/H3/ST/CNT/CN (BC fully written by pass2; CAND claimed)
    hipMemsetAsync(d_ws, 0, (size_t)ZERO_END * sizeof(unsigned), stream);

    hipLaunchKernelGGL(hist1_k,  dim3(Bn * 250),  dim3(256), 0, stream, cube, ws);
    hipLaunchKernelGGL(pick1_k,  dim3(Bn),        dim3(256), 0, stream, ws);
    hipLaunchKernelGGL(pass2_k,  dim3(Bn * 1000), dim3(256), 0, stream, cube, ws);
    hipLaunchKernelGGL(candh2_k, dim3(Bn * 32),   dim3(256), 0, stream, ws);
    hipLaunchKernelGGL(pick2_k,  dim3(Bn),        dim3(256), 0, stream, ws);
    hipLaunchKernelGGL(candh3_k, dim3(Bn * 8),    dim3(256), 0, stream, ws);
    hipLaunchKernelGGL(pick3_k,  dim3(Bn),        dim3(256), 0, stream, ws);
    hipLaunchKernelGGL(fixup_k,  dim3(Bn * 16),   dim3(256), 0, stream, ws);
    hipLaunchKernelGGL(scan_k,   dim3(Bn),        dim3(256), 0, stream, ws);
    hipLaunchKernelGGL(scatter_k, dim3(Bn * 1000), dim3(256), 0, stream, cube, dop, out, ws);
}